// Round 7
// baseline (87.411 us; speedup 1.0000x reference)
//
#include <hip/hip_runtime.h>

// TileRenderer: out[p,b,y,x] = sum_s bilinear_sample(sources[p,s,b], affine(locs[p,s]))
// n_ptiles=1024, max_src=4, n_bands=5, ptile_slen=52.
//
// Affine (exact): l = (loc*(4/52) + 24/52 - 0.5)*2
//   ix = x*(25.5/26) + (1-l1)*25.5 - 25.5^2/26   (grid[...,0] uses swapped l)
//   iy = y*(25.5/26) + (1-l0)*25.5 - 25.5^2/26
// For locs in [0,1]: floor(ix), floor(iy) in [-2,52].
//
// Structure = round-6 (proven): global_load_lds staging into a y-padded
// linear LDS buffer (rows -2..53, interior one contiguous 2704-float block),
// double-buffer, one barrier per source.
// New in round-7: COLUMN-STRIP thread mapping. Thread = (x = tid&63,
// yg = tid>>6); each thread owns one fixed column x and 13 rows y = yg+4k.
// The x-side of the bilinear (ix, floor, wx, masks, clamp, column base) is
// computed ONCE per source instead of once per pixel; the per-row work is
// 5 VALU y-side + 2 ds_read2_b32 + 7 math. Lanes x>=52 compute garbage
// (reads stay in-bounds via the clamp) and are masked at the store.
constexpr int NP = 1024;
constexpr int MS = 4;
constexpr int NB = 5;
constexpr int SL = 52;
constexpr int SS = SL * SL;     // 2704
constexpr int NTHR = 256;
constexpr int NROW = 13;        // rows per thread (4 y-groups * 13 = 52)
constexpr int NCH = SS / 4;     // 676 float4 chunks per slice
constexpr int FPAD = 4;         // front/tail pad (floats)
constexpr int PY = 2;           // zero pad rows above/below
constexpr int BUFF = FPAD + (SL + 2 * PY) * SL + FPAD;  // 2920 floats
constexpr int INT0 = FPAD + PY * SL;  // 108: interior (row0,col0); byte 432, 16B-mult
constexpr int PADF = 2 * (FPAD + PY * SL);  // 216 pad floats per buffer

__device__ __forceinline__ void gload_lds16(const float* g, float* l) {
    __builtin_amdgcn_global_load_lds(
        (const __attribute__((address_space(1))) void*)g,
        (__attribute__((address_space(3))) void*)l,
        16, 0, 0);
}

__global__ __launch_bounds__(NTHR) void tile_render_kernel(
    const float* __restrict__ locs,
    const float* __restrict__ sources,
    float* __restrict__ out)
{
    __shared__ __align__(16) float smem[2 * BUFF];  // 23360 B -> 7 blocks/CU

    const int blk = blockIdx.x;
    const int p = blk / NB;
    const int b = blk - p * NB;
    const int tid = threadIdx.x;

    // Zero ONLY the pad regions (disjoint from the staged interior, so no
    // barrier is needed between this and staging; the first loop barrier
    // publishes both). Front pads: floats [0,108); back: [2812,2920).
    if (tid < PADF) {
        int off = (tid < INT0) ? tid : (SS + tid);  // 2704+108..2704+215 = 2812..2919
        smem[off] = 0.0f;
        smem[BUFF + off] = 0.0f;
    }

    const float A = 25.5f / 26.0f;
    float bx[MS], by[MS];
    #pragma unroll
    for (int s = 0; s < MS; ++s) {
        float loc0 = locs[(p * MS + s) * 2 + 0];
        float loc1 = locs[(p * MS + s) * 2 + 1];
        float l0 = (loc0 * (4.0f / 52.0f) + (24.0f / 52.0f) - 0.5f) * 2.0f;
        float l1 = (loc1 * (4.0f / 52.0f) + (24.0f / 52.0f) - 0.5f) * 2.0f;
        bx[s] = (1.0f - l1) * 25.5f - 25.5f * 25.5f / 26.0f;
        by[s] = (1.0f - l0) * 25.5f - 25.5f * 25.5f / 26.0f;
    }

    const int x = tid & 63;        // column (52 active, 12 masked at store)
    const int yg = tid >> 6;       // y-group: rows yg, yg+4, ..., yg+48
    const float fxv = (float)x;

    const float* gsrc = sources + ((size_t)p * MS * NB + b) * SS;
    auto stage = [&](float* buf, int s) {
        const float* g = gsrc + (size_t)s * (NB * SS);
        float* dst = buf + INT0;
        gload_lds16(g + 4 * tid,          dst + 4 * tid);
        gload_lds16(g + 4 * (tid + NTHR), dst + 4 * (tid + NTHR));
        if (tid < NCH - 2 * NTHR)
            gload_lds16(g + 4 * (tid + 2 * NTHR), dst + 4 * (tid + 2 * NTHR));
    };

    float acc[NROW];
    #pragma unroll
    for (int k = 0; k < NROW; ++k) acc[k] = 0.0f;

    stage(smem, 0);

    #pragma unroll
    for (int s = 0; s < MS; ++s) {
        // Barrier drains vmcnt: buffer for s (and the pad zeros on s=0) is
        // ready; all reads of the other buffer are done -> restage is safe.
        __syncthreads();
        if (s < MS - 1) stage(smem + ((s + 1) & 1) * BUFF, s + 1);

        const float* cur = smem + (s & 1) * BUFF;
        // ---- x-side: once per source ----
        float ix = fmaf(fxv, A, bx[s]);
        float ixf = floorf(ix);
        float wx = ix - ixf;
        int xi = (int)ixf;
        float wxa = ((unsigned)xi       <= 51u) ? (1.0f - wx) : 0.0f;
        float wxb = ((unsigned)(xi + 1) <= 51u) ? wx          : 0.0f;
        int xc = min(max(xi, -1), SL - 1);
        const float* colbase = cur + (xc + INT0);
        const float bys = by[s];
        // ---- per-row: y-side + taps ----
        #pragma unroll
        for (int k = 0; k < NROW; ++k) {
            float fyv = (float)(yg + 4 * k);
            float iy = fmaf(fyv, A, bys);
            float iyf = floorf(iy);
            float wy = iy - iyf;
            int yi = (int)iyf;
            const float* q = colbase + yi * SL;
            float v00 = q[0],  v01 = q[1];        // ds_read2_b32
            float v10 = q[SL], v11 = q[SL + 1];   // ds_read2_b32
            float h0 = fmaf(v01, wxb, v00 * wxa);
            float h1 = fmaf(v11, wxb, v10 * wxa);
            acc[k] = fmaf(wy, h1 - h0, h0 + acc[k]);
        }
    }

    if (x < SL) {
        float* outp = out + ((size_t)p * NB + b) * SS + x;
        #pragma unroll
        for (int k = 0; k < NROW; ++k)
            outp[(yg + 4 * k) * SL] = acc[k];
    }
}

extern "C" void kernel_launch(void* const* d_in, const int* in_sizes, int n_in,
                              void* d_out, int out_size, void* d_ws, size_t ws_size,
                              hipStream_t stream) {
    const float* locs = (const float*)d_in[0];
    const float* sources = (const float*)d_in[1];
    float* out = (float*)d_out;
    dim3 grid(NP * NB);
    dim3 block(NTHR);
    hipLaunchKernelGGL(tile_render_kernel, grid, block, 0, stream,
                       locs, sources, out);
}

// Round 8
// 47.427 us; speedup vs baseline: 1.8430x; 1.8430x over previous
//
#include <hip/hip_runtime.h>

// TileRenderer: out[p,b,y,x] = sum_s bilinear_sample(sources[p,s,b], affine(locs[p,s]))
// n_ptiles=1024, max_src=4, n_bands=5, ptile_slen=52.
//
// Affine (exact): l = (loc*(4/52) + 24/52 - 0.5)*2
//   ix = x*(25.5/26) + (1-l1)*25.5 - 25.5^2/26   (grid[...,0] uses swapped l)
//   iy = y*(25.5/26) + (1-l0)*25.5 - 25.5^2/26
// For locs in [0,1]: floor(ix), floor(iy) in [-2,52].
//
// Structure = round-6 verbatim (48.9 us, proven): global_load_lds staging
// into a y-padded linear LDS buffer (rows -2..53, interior one contiguous
// 2704-float block), double-buffer, one barrier per source, row-major
// pixel-per-lane compute.
// ONE change this round: output stores are NON-TEMPORAL. Output (54 MB) is
// write-once/never-read; letting it allocate in L3 pushed the working set to
// 275 MB > 256 MB L3 and evicted ~half the input each replay (FETCH=107 MB
// vs 221 MB logical reads). nt stores keep the input L3-resident.
constexpr int NP = 1024;
constexpr int MS = 4;
constexpr int NB = 5;
constexpr int SL = 52;
constexpr int SS = SL * SL;     // 2704
constexpr int NTHR = 256;
constexpr int NJ = 11;          // ceil(SS/256)
constexpr int TAIL = SS - (NJ - 1) * NTHR;  // 144
constexpr int NCH = SS / 4;     // 676 float4 chunks
constexpr int FPAD = 4;         // front/tail pad (floats)
constexpr int PY = 2;           // zero pad rows above/below
constexpr int BUFF = FPAD + (SL + 2 * PY) * SL + FPAD;  // 4+2912+4 = 2920
constexpr int INT0 = FPAD + PY * SL;  // 108: interior (row0,col0); 432B, 16B-mult

__device__ __forceinline__ void gload_lds16(const float* g, float* l) {
    __builtin_amdgcn_global_load_lds(
        (const __attribute__((address_space(1))) void*)g,
        (__attribute__((address_space(3))) void*)l,
        16, 0, 0);
}

__global__ __launch_bounds__(NTHR) void tile_render_kernel(
    const float* __restrict__ locs,
    const float* __restrict__ sources,
    float* __restrict__ out)
{
    __shared__ __align__(16) float smem[2 * BUFF];  // 23360 B -> 7 blocks/CU

    const int blk = blockIdx.x;
    const int p = blk / NB;
    const int b = blk - p * NB;
    const int tid = threadIdx.x;

    // Zero both buffers (pads must be genuine zeros; interior re-staged).
    for (int i = 4 * tid; i < 2 * BUFF; i += 4 * NTHR)
        *reinterpret_cast<float4*>(smem + i) = make_float4(0.f, 0.f, 0.f, 0.f);

    const float A = 25.5f / 26.0f;
    float bx[MS], by[MS];
    #pragma unroll
    for (int s = 0; s < MS; ++s) {
        float loc0 = locs[(p * MS + s) * 2 + 0];
        float loc1 = locs[(p * MS + s) * 2 + 1];
        float l0 = (loc0 * (4.0f / 52.0f) + (24.0f / 52.0f) - 0.5f) * 2.0f;
        float l1 = (loc1 * (4.0f / 52.0f) + (24.0f / 52.0f) - 0.5f) * 2.0f;
        bx[s] = (1.0f - l1) * 25.5f - 25.5f * 25.5f / 26.0f;
        by[s] = (1.0f - l0) * 25.5f - 25.5f * 25.5f / 26.0f;
    }

    // Hoisted per-thread pixel coords (j = NJ-1 dummy-safe for tid >= TAIL).
    float fx[NJ], fy[NJ];
    #pragma unroll
    for (int j = 0; j < NJ; ++j) {
        int pix = tid + j * NTHR;
        if (pix >= SS) pix = 0;
        int y = pix / SL;
        fx[j] = (float)(pix - y * SL);
        fy[j] = (float)y;
    }

    const float* gsrc = sources + ((size_t)p * MS * NB + b) * SS;
    auto stage = [&](float* buf, int s) {
        const float* g = gsrc + (size_t)s * (NB * SS);
        float* dst = buf + INT0;
        gload_lds16(g + 4 * tid,          dst + 4 * tid);
        gload_lds16(g + 4 * (tid + NTHR), dst + 4 * (tid + NTHR));
        if (tid < NCH - 2 * NTHR)
            gload_lds16(g + 4 * (tid + 2 * NTHR), dst + 4 * (tid + 2 * NTHR));
    };

    float acc[NJ];
    #pragma unroll
    for (int j = 0; j < NJ; ++j) acc[j] = 0.0f;

    __syncthreads();        // zero-init visible before staging overwrites
    stage(smem, 0);

    #pragma unroll
    for (int s = 0; s < MS; ++s) {
        // Barrier drains vmcnt: buffer for s is ready; all reads of the
        // other buffer (s-1's compute) are also done, so restaging is safe.
        __syncthreads();
        if (s < MS - 1) stage(smem + ((s + 1) & 1) * BUFF, s + 1);

        const float* cur = smem + (s & 1) * BUFF;
        const float bxs = bx[s], bys = by[s];
        #pragma unroll
        for (int j = 0; j < NJ; ++j) {
            float ix = fmaf(fx[j], A, bxs);
            float iy = fmaf(fy[j], A, bys);
            float ixf = floorf(ix);
            float iyf = floorf(iy);
            float wx = ix - ixf;
            float wy = iy - iyf;
            int xi = (int)ixf;
            int yi = (int)iyf;
            float wx0 = 1.0f - wx;
            // x: zeros-padding folded into weights; tap base clamped so the
            // {xc, xc+1} pair covers every valid corner, OOB half masked.
            float wxa = ((unsigned)xi       <= 51u) ? wx0 : 0.0f;
            float wxb = ((unsigned)(xi + 1) <= 51u) ? wx  : 0.0f;
            int xc = min(max(xi, -1), SL - 1);
            // y: no mask, no clamp — pad rows are zeros; r1 = r0 + 52 static.
            const float* q = cur + (yi * SL + (xc + INT0));
            float v00 = q[0],  v01 = q[1];        // ds_read2_b32
            float v10 = q[SL], v11 = q[SL + 1];   // ds_read2_b32
            float h0 = fmaf(v01, wxb, v00 * wxa);
            float h1 = fmaf(v11, wxb, v10 * wxa);
            acc[j] = fmaf(wy, h1 - h0, h0 + acc[j]);
        }
    }

    float* outp = out + ((size_t)p * NB + b) * SS;
    #pragma unroll
    for (int j = 0; j < NJ; ++j) {
        int pix = tid + j * NTHR;
        if (j < NJ - 1 || tid < TAIL)
            __builtin_nontemporal_store(acc[j], outp + pix);
    }
}

extern "C" void kernel_launch(void* const* d_in, const int* in_sizes, int n_in,
                              void* d_out, int out_size, void* d_ws, size_t ws_size,
                              hipStream_t stream) {
    const float* locs = (const float*)d_in[0];
    const float* sources = (const float*)d_in[1];
    float* out = (float*)d_out;
    dim3 grid(NP * NB);
    dim3 block(NTHR);
    hipLaunchKernelGGL(tile_render_kernel, grid, block, 0, stream,
                       locs, sources, out);
}